// Round 1
// baseline (1168.374 us; speedup 1.0000x reference)
//
#include <hip/hip_runtime.h>
#include <hip/hip_bf16.h>

#define DK 256      // inner dim (d)
#define NC 128      // GEMM output cols (4K)
#define EPSV 1e-6f

typedef __bf16 bf16x8 __attribute__((ext_vector_type(8)));
typedef __bf16 bf16x4 __attribute__((ext_vector_type(4)));
typedef float f32x4 __attribute__((ext_vector_type(4)));

// ws layout (floats): [0..31] Usum, [32..63] s, [64..1087] VtZ, [1088] D

// Kernel 1: X = relu(x@W + b). U -> out[:,0:32], T -> out[:,32:64];
// accumulate Usum, s (VALU partials) and VtZ (register-resident MFMA) into accg.
// Block = 512 thr = 8 waves. Each wave owns 16 rows x ALL 128 cols (no duplicate
// x loads). Chunk = 128 rows/block. BARRIER-FREE main loop: VtZ is accumulated
// per-wave from epilogue registers via zero-padded 16x16x32 MFMA (lane(quad,l16)
// holds X[n=quad*4+r][col=l16] == A/B fragment element k=quad*8+j, j=r, with
// j=4..7 zeroed), so no Vt/Zt LDS round-trip and no per-chunk __syncthreads.
__global__ __launch_bounds__(512, 4) void k_gemm(
    const float* __restrict__ x, const float* __restrict__ W,
    const float* __restrict__ bias, float* __restrict__ out,
    float* __restrict__ accg, int N)
{
  // B-fragment layout: frag index f = (kk*4+quad)*128 + n, 8 bf16 each (16 B)
  __shared__ __bf16 Wlds[32768];          // 64 KB; reused as vred (32 KB) at end
  __shared__ float  redS[64];

  const int tid  = threadIdx.x;
  const int wave = tid >> 6;
  const int lane = tid & 63;
  const int quad = lane >> 4;
  const int l16  = lane & 15;

  // --- stage W into LDS as bf16 fragments (once per block; W is L2-hot) ---
  for (int f = tid; f < 4096; f += 512) {
    const int n  = f & 127;
    const int qk = f >> 7;                 // kk*4 + quad
    const int k0 = (qk >> 2) * 32 + (qk & 3) * 8;
    bf16x8 w;
    #pragma unroll
    for (int j = 0; j < 8; ++j) w[j] = (__bf16)W[(size_t)(k0 + j) * NC + n];
    *(bf16x8*)&Wlds[f * 8] = w;
  }
  float bias8[8];
  #pragma unroll
  for (int t = 0; t < 8; ++t) bias8[t] = bias[t * 16 + l16];
  if (tid < 64) redS[tid] = 0.f;
  __syncthreads();                         // only barrier before the end-reduction

  float usumv[2] = {0.f, 0.f};
  float ssumv[2] = {0.f, 0.f};
  f32x4 vz[4];                             // VtZ acc, [vt*2+zt]; f32x4 over r
  #pragma unroll
  for (int t = 0; t < 4; ++t) vz[t] = (f32x4){0.f, 0.f, 0.f, 0.f};

  const int nchunks = (N + 127) >> 7;
  for (int c = blockIdx.x; c < nchunks; c += gridDim.x) {
    const int rbase = c << 7;
    const int arow  = rbase + wave * 16 + l16;   // A-fragment row: m = l16
    const bool rv   = arow < N;
    const float* xr = x + (size_t)arow * DK;

    // issue all x loads for this chunk upfront (16 VMEM in flight per lane)
    f32x4 xv[16];
    #pragma unroll
    for (int kk = 0; kk < 8; ++kk) {
      const int koff = kk * 32 + quad * 8;       // A: k = quad*8 + j
      xv[2 * kk]     = rv ? *(const f32x4*)(xr + koff)     : (f32x4){0.f,0.f,0.f,0.f};
      xv[2 * kk + 1] = rv ? *(const f32x4*)(xr + koff + 4) : (f32x4){0.f,0.f,0.f,0.f};
    }
    // convert to bf16 A-fragments (xv regs die here -> af is 32 VGPRs)
    bf16x8 af[8];
    #pragma unroll
    for (int kk = 0; kk < 8; ++kk) {
      bf16x8 a;
      a[0] = (__bf16)xv[2*kk].x;   a[1] = (__bf16)xv[2*kk].y;
      a[2] = (__bf16)xv[2*kk].z;   a[3] = (__bf16)xv[2*kk].w;
      a[4] = (__bf16)xv[2*kk+1].x; a[5] = (__bf16)xv[2*kk+1].y;
      a[6] = (__bf16)xv[2*kk+1].z; a[7] = (__bf16)xv[2*kk+1].w;
      af[kk] = a;
    }

    const int orow0 = rbase + wave * 16 + quad * 4;  // C/D: col=l16, row=quad*4+r
    bf16x4 pv[2], pz[2];

    // ---- pass 1: ntl 0..3 -> U (X cols 0..31) + V (X cols 32..63) ----
    {
      f32x4 acc[4];
      #pragma unroll
      for (int t = 0; t < 4; ++t) acc[t] = (f32x4){0.f, 0.f, 0.f, 0.f};
      #pragma unroll
      for (int kk = 0; kk < 8; ++kk)
        #pragma unroll
        for (int ntl = 0; ntl < 4; ++ntl) {
          const bf16x8 bf = *(const bf16x8*)&Wlds[(((kk << 2) | quad) * 128
                                                  + ntl * 16 + l16) * 8];
          acc[ntl] = __builtin_amdgcn_mfma_f32_16x16x32_bf16(af[kk], bf, acc[ntl], 0, 0, 0);
        }
      #pragma unroll
      for (int ntl = 0; ntl < 4; ++ntl) {
        float v4[4];
        #pragma unroll
        for (int r = 0; r < 4; ++r) {
          float v = acc[ntl][r] + bias8[ntl];
          v = fmaxf(v, 0.f);
          if (orow0 + r >= N) v = 0.f;             // mask tail rows out of reductions
          v4[r] = v;
        }
        if (ntl < 2) {                             // U -> out cols 0..31, + Usum
          #pragma unroll
          for (int r = 0; r < 4; ++r) {
            if (orow0 + r < N) out[(size_t)(orow0 + r) * 64 + ntl * 16 + l16] = v4[r];
            usumv[ntl] += v4[r];
          }
        } else {                                   // V: s-sum + pack for VtZ MFMA
          ssumv[ntl - 2] += v4[0] + v4[1] + v4[2] + v4[3];
          bf16x4 p;
          p[0] = (__bf16)v4[0]; p[1] = (__bf16)v4[1];
          p[2] = (__bf16)v4[2]; p[3] = (__bf16)v4[3];
          pv[ntl - 2] = p;
        }
      }
    }
    // ---- pass 2: ntl 4..7 -> Z (X cols 64..95) + T (X cols 96..127) ----
    {
      f32x4 acc[4];
      #pragma unroll
      for (int t = 0; t < 4; ++t) acc[t] = (f32x4){0.f, 0.f, 0.f, 0.f};
      #pragma unroll
      for (int kk = 0; kk < 8; ++kk)
        #pragma unroll
        for (int ntl = 0; ntl < 4; ++ntl) {
          const bf16x8 bf = *(const bf16x8*)&Wlds[(((kk << 2) | quad) * 128
                                                  + (ntl + 4) * 16 + l16) * 8];
          acc[ntl] = __builtin_amdgcn_mfma_f32_16x16x32_bf16(af[kk], bf, acc[ntl], 0, 0, 0);
        }
      #pragma unroll
      for (int ntl = 0; ntl < 4; ++ntl) {
        float v4[4];
        #pragma unroll
        for (int r = 0; r < 4; ++r) {
          float v = acc[ntl][r] + bias8[ntl + 4];
          v = fmaxf(v, 0.f);
          if (orow0 + r >= N) v = 0.f;
          v4[r] = v;
        }
        if (ntl < 2) {                             // Z: pack for VtZ MFMA
          bf16x4 p;
          p[0] = (__bf16)v4[0]; p[1] = (__bf16)v4[1];
          p[2] = (__bf16)v4[2]; p[3] = (__bf16)v4[3];
          pz[ntl] = p;
        } else {                                   // T -> out cols 32..63
          #pragma unroll
          for (int r = 0; r < 4; ++r)
            if (orow0 + r < N)
              out[(size_t)(orow0 + r) * 64 + 32 + (ntl - 2) * 16 + l16] = v4[r];
        }
      }
    }
    // ---- VtZ += V^T @ Z for this wave's 16 rows: zero-padded k (j=4..7 = 0) ----
    #pragma unroll
    for (int vt = 0; vt < 2; ++vt) {
      bf16x8 av;
      av[0] = pv[vt][0]; av[1] = pv[vt][1]; av[2] = pv[vt][2]; av[3] = pv[vt][3];
      av[4] = (__bf16)0.f; av[5] = (__bf16)0.f; av[6] = (__bf16)0.f; av[7] = (__bf16)0.f;
      #pragma unroll
      for (int zt = 0; zt < 2; ++zt) {
        bf16x8 bz;
        bz[0] = pz[zt][0]; bz[1] = pz[zt][1]; bz[2] = pz[zt][2]; bz[3] = pz[zt][3];
        bz[4] = (__bf16)0.f; bz[5] = (__bf16)0.f; bz[6] = (__bf16)0.f; bz[7] = (__bf16)0.f;
        vz[vt * 2 + zt] = __builtin_amdgcn_mfma_f32_16x16x32_bf16(av, bz, vz[vt * 2 + zt], 0, 0, 0);
      }
    }
  }

  // ---- end-of-kernel reductions ----
  // Usum/s: LDS atomics (all 8 waves contribute), then one global add set
  #pragma unroll
  for (int t = 0; t < 2; ++t) {
    atomicAdd(&redS[t * 16 + l16],      usumv[t]);
    atomicAdd(&redS[32 + t * 16 + l16], ssumv[t]);
  }
  __syncthreads();                       // also: everyone done reading Wlds
  if (tid < 64) atomicAdd(&accg[tid], redS[tid]);

  // VtZ: reduce 8 waves' tiles through LDS (reuse Wlds), 1024 atomics/block
  float* vred = (float*)Wlds;
  #pragma unroll
  for (int vt = 0; vt < 2; ++vt)
    #pragma unroll
    for (int zt = 0; zt < 2; ++zt)
      #pragma unroll
      for (int r = 0; r < 4; ++r)
        vred[wave * 1024 + (vt * 16 + quad * 4 + r) * 32 + zt * 16 + l16] = vz[vt * 2 + zt][r];
  __syncthreads();
  for (int e = tid; e < 1024; e += 512) {
    float s = 0.f;
    #pragma unroll
    for (int w = 0; w < 8; ++w) s += vred[w * 1024 + e];
    atomicAdd(&accg[64 + e], s);
  }
}

// Kernel 2: D = 1 / (Usum . s / N + EPS)
__global__ void k_norm(float* __restrict__ accg, int N) {
  const int t = threadIdx.x;
  float p = 0.f;
  if (t < 32) p = accg[t] * accg[32 + t];
  #pragma unroll
  for (int off = 16; off >= 1; off >>= 1) p += __shfl_down(p, off);
  if (t == 0) accg[1088] = 1.0f / (p / (float)N + EPSV);
}

// Kernel 3: in-place out[:,0:32] = U @ (VtZ * D). One block per 64-row group.
__global__ __launch_bounds__(256) void k_res(float* __restrict__ out,
                                             const float* __restrict__ accg, int N) {
  __shared__ float Ms[32 * 33];
  __shared__ float Us[64 * 33];
  const float D = accg[1088];
  for (int i = threadIdx.x; i < 1024; i += 256)
    Ms[(i >> 5) * 33 + (i & 31)] = accg[64 + i] * D;
  const int j  = threadIdx.x & 31;
  const int r0 = threadIdx.x >> 5;  // 0..7
  const int rbase = blockIdx.x * 64;
  #pragma unroll
  for (int i = 0; i < 8; ++i) {
    const int lr = r0 + i * 8;
    const int row = rbase + lr;
    Us[lr * 33 + j] = (row < N) ? out[(size_t)row * 64 + j] : 0.f;
  }
  __syncthreads();     // Ms ready + all U staged before any in-place overwrite
  #pragma unroll
  for (int i = 0; i < 8; ++i) {
    const int lr = r0 + i * 8;
    const int row = rbase + lr;
    if (row < N) {
      float a = 0.f;
      #pragma unroll
      for (int k = 0; k < 32; ++k) a += Us[lr * 33 + k] * Ms[k * 33 + j];
      out[(size_t)row * 64 + j] = a;
    }
  }
}

extern "C" void kernel_launch(void* const* d_in, const int* in_sizes, int n_in,
                              void* d_out, int out_size, void* d_ws, size_t ws_size,
                              hipStream_t stream) {
  const float* x    = (const float*)d_in[0];
  const float* W    = (const float*)d_in[1];
  const float* b    = (const float*)d_in[2];
  float* out  = (float*)d_out;
  float* accg = (float*)d_ws;
  const int N = in_sizes[0] / DK;
  const int ngroups = (N + 63) >> 6;

  hipMemsetAsync(accg, 0, 1089 * sizeof(float), stream);  // zero accumulators (capture-safe)
  hipLaunchKernelGGL(k_gemm, dim3(512),     dim3(512), 0, stream, x, W, b, out, accg, N);
  hipLaunchKernelGGL(k_norm, dim3(1),       dim3(64),  0, stream, accg, N);
  hipLaunchKernelGGL(k_res,  dim3(ngroups), dim3(256), 0, stream, out, accg, N);
}